// Round 1
// 7685.063 us; speedup vs baseline: 1.1010x; 1.1010x over previous
//
#include <hip/hip_runtime.h>
#include <hip/hip_bf16.h>
#include <math.h>

// Dims: D=32, T=32, H=64, B=128, F=2048, 3F=6144, N=4096.
// Scan over axis 0 (128 sequential steps), state (32,2048). All I/O fp32.
// Round-5: persistent per-phase GRU kernel. 256 blocks x 512 threads (8 waves,
// 2 waves/SIMD, <=256 VGPR => 1 block/CU => co-resident). Whh K-slices held in
// VGPRs (128/lane) across all 32 steps of a phase; manual monotone grid
// barrier between steps (counter in gbuf head, dead until tail). Packed r|z
// MFMA B-fragment (16 distinct rows). Split-precision (hi/lo bf16) 3-term
// MFMA retained from round-4 for accuracy.
//
// Workspace (bytes), total 161,873,920 (~154 MB):
//   WihH  [0,          25165824)  bf16 hi
//   WihL  [25165824,   50331648)  bf16 lo
//   WhhH  [50331648,   75497472)
//   WhhL  [75497472,  100663296)
//   gi    [100663296, 125829120)  fp32 (1024,6144) per 32-step phase
//   XYEhi [125829120, 142606336)  bf16 (4096,2048): X -> ys0 -> emb
//   XYElo [142606336, 159383552)
//   h32   [159383552, 159645696)  fp32 (32,2048) phase handoff
//   z16   [159645696, 159776768)  bf16 zeros (t=0 state)
//   attv  [159776768, 160825344)  fp32 (128,2048)
//   gbuf  [160825344, 161873920)  fp32 (128,2048); first 4 B = barrier counter
//                                 during recurrence (gbuf dead until k_gat)
//   priors[0, 33554432) fp32 — overlaps Wih pair (dead at tail)

typedef __bf16 bf16;
typedef __attribute__((ext_vector_type(4))) __bf16 bf16x4;
typedef __attribute__((ext_vector_type(8))) __bf16 bf16x8;
typedef __attribute__((ext_vector_type(4))) float f32x4;

#define AS1 __attribute__((address_space(1)))
#define AS3 __attribute__((address_space(3)))

__device__ __forceinline__ void gll16(const void* g, void* s) {
  __builtin_amdgcn_global_load_lds((const AS1 void*)g, (AS3 void*)s, 16, 0, 0);
}
__device__ __forceinline__ float sigm(float x) { return 1.0f/(1.0f + expf(-x)); }
#define MFMA __builtin_amdgcn_mfma_f32_16x16x32_bf16

// ---------------- fp32 -> (hi, lo) bf16 split
__global__ __launch_bounds__(256) void k_split(const float4* __restrict__ in,
                                               bf16x4* __restrict__ hi,
                                               bf16x4* __restrict__ lo, int nvec) {
  int i = blockIdx.x*256 + threadIdx.x;
  if (i >= nvec) return;
  float4 v = in[i];
  bf16x4 h, l;
  h[0]=(bf16)v.x; l[0]=(bf16)(v.x-(float)h[0]);
  h[1]=(bf16)v.y; l[1]=(bf16)(v.y-(float)h[1]);
  h[2]=(bf16)v.z; l[2]=(bf16)(v.z-(float)h[2]);
  h[3]=(bf16)v.w; l[3]=(bf16)(v.w-(float)h[3]);
  hi[i] = h; lo[i] = l;
}

// ---------------- nan_to_num + split
__device__ __forceinline__ float fixv(float x) {
  if (isnan(x)) return 0.f;
  if (isinf(x)) return (x > 0.f) ? 1.0f : -3.4028234663852886e38f;
  return x;
}
__global__ __launch_bounds__(256) void k_prep(const float4* __restrict__ in,
                                              bf16x4* __restrict__ hi,
                                              bf16x4* __restrict__ lo, int nvec) {
  int i = blockIdx.x*256 + threadIdx.x;
  if (i >= nvec) return;
  float4 v = in[i];
  v.x = fixv(v.x); v.y = fixv(v.y); v.z = fixv(v.z); v.w = fixv(v.w);
  bf16x4 h, l;
  h[0]=(bf16)v.x; l[0]=(bf16)(v.x-(float)h[0]);
  h[1]=(bf16)v.y; l[1]=(bf16)(v.y-(float)h[1]);
  h[2]=(bf16)v.z; l[2]=(bf16)(v.z-(float)h[2]);
  h[3]=(bf16)v.w; l[3]=(bf16)(v.w-(float)h[3]);
  hi[i] = h; lo[i] = l;
}

// ---------------- C(M,N) fp32 = (Ah+Al)(M,K) @ (Bh+Bl)(N,K)^T + bias
// 3-term split-precision MFMA: AhBh + AlBh + AhBl. 128x128 tile, 4 waves, BK=64.
__global__ __launch_bounds__(256) void k_gemm3(
    const bf16* __restrict__ Ah, const bf16* __restrict__ Al,
    const bf16* __restrict__ Bh, const bf16* __restrict__ Bl,
    const float* __restrict__ bias, float* __restrict__ C,
    int M, int N, int K)
{
  __shared__ bf16x8 AsH[1024], AsL[1024], BsH[1024], BsL[1024];
  const int tid = threadIdx.x;
  const int w = tid >> 6, l = tid & 63;
  const int lm = l & 15, lk = l >> 4;
  const int m0 = blockIdx.y * 128, n0 = blockIdx.x * 128;
  const int wm = w & 1, wn = w >> 1;

  f32x4 acc[4][4];
#pragma unroll
  for (int i = 0; i < 4; i++)
#pragma unroll
    for (int j = 0; j < 4; j++) acc[i][j] = (f32x4){0.f,0.f,0.f,0.f};

  const int row_s = (w*64 + l) >> 3;
  const int s_s   = l & 7;

  for (int k0 = 0; k0 < K; k0 += 64) {
#pragma unroll
    for (int q = 0; q < 4; q++) {
      int row = q*32 + row_s;
      size_t offA = (size_t)(m0+row)*K + k0 + s_s*8;
      size_t offB = (size_t)(n0+row)*K + k0 + s_s*8;
      gll16(Ah + offA, &AsH[q*256 + w*64]);
      gll16(Al + offA, &AsL[q*256 + w*64]);
      gll16(Bh + offB, &BsH[q*256 + w*64]);
      gll16(Bl + offB, &BsL[q*256 + w*64]);
    }
    __syncthreads();
#pragma unroll
    for (int ko = 0; ko < 2; ko++) {
      const int kgl = ko*4 + lk;
      bf16x8 aFh[4], aFl[4], bFh[4], bFl[4];
#pragma unroll
      for (int mt = 0; mt < 4; mt++) {
        int r = (wm*64 + mt*16 + lm)*8 + kgl;
        aFh[mt] = AsH[r]; aFl[mt] = AsL[r];
      }
#pragma unroll
      for (int nt = 0; nt < 4; nt++) {
        int r = (wn*64 + nt*16 + lm)*8 + kgl;
        bFh[nt] = BsH[r]; bFl[nt] = BsL[r];
      }
#pragma unroll
      for (int mt = 0; mt < 4; mt++)
#pragma unroll
        for (int nt = 0; nt < 4; nt++) {
          acc[mt][nt] = MFMA(aFh[mt], bFh[nt], acc[mt][nt], 0,0,0);
          acc[mt][nt] = MFMA(aFl[mt], bFh[nt], acc[mt][nt], 0,0,0);
          acc[mt][nt] = MFMA(aFh[mt], bFl[nt], acc[mt][nt], 0,0,0);
        }
    }
    __syncthreads();
  }

  // C/D: col = lane&15, row = (lane>>4)*4 + reg
#pragma unroll
  for (int nt = 0; nt < 4; nt++) {
    int col = n0 + wn*64 + nt*16 + lm;
    float bv = bias[col];
#pragma unroll
    for (int mt = 0; mt < 4; mt++) {
      int rowb = m0 + wm*64 + mt*16 + lk*4;
#pragma unroll
      for (int r = 0; r < 4; r++)
        C[(size_t)(rowb + r)*N + col] = acc[mt][nt][r] + bv;
    }
  }
}

// ---------------- persistent GRU phase: 32 steps in one kernel.
// 256 blocks x 512 threads (8 waves). Block owns 8 units (u0..u0+7).
// Wave w covers K-slice [w*256, w*256+256); its Whh hi/lo fragments are held
// in VGPRs across all 32 steps (32 x bf16x8 = 128 VGPR/lane).
// B-frag "RZ": N-rows lm<8 -> r-gate unit lm, lm>=8 -> z-gate unit lm-8.
// B-frag "N2": n-gate rows, lm&7 (2x dup, cols 8-15 of acc unused dup).
// Per step: MFMA partials -> LDS -> 512-thread cross-wave reduce -> waves 0/1
// compute gates (h carried in regs) -> store ys hi/lo -> grid barrier.
// Grid barrier: monotone counter, agent-scope atomics + __threadfence (wbl2/
// inv handles cross-XCD L2 non-coherence). All 256 blocks co-resident:
// 8 waves <=256 VGPR => exactly 1 block/CU on 256 CUs.
__global__ __launch_bounds__(512, 2) void k_gru_phase(
    const bf16* __restrict__ WhH, const bf16* __restrict__ WhL,  // (6144,2048)
    const float* __restrict__ bhh,
    const float* __restrict__ gi,     // (1024,6144) fp32 for this phase (incl bih)
    float* __restrict__ h32,          // (32,2048) fp32 phase handoff
    bf16* XYEhi, bf16* XYElo,         // full (4096,2048) buffers (read t-1, write t)
    const bf16* __restrict__ z16,     // zeros for t==0
    int t0_abs, unsigned* bar, unsigned bar_base)
{
  __shared__ float red[8704];         // [8 waves][64 lanes][17]
  const int tid = threadIdx.x;
  const int w = tid >> 6, l = tid & 63;
  const int lm = l & 15, lk = l >> 4;
  const int u0 = blockIdx.x * 8;

  // ---- weight fragments, loaded once, live in regs for all 32 steps
  const size_t koff = (size_t)(w*256 + lk*8);
  const int urz = u0 + (lm & 7);
  const size_t rz_row = (size_t)((lm >> 3)*2048 + urz);   // gate 0 (r) or 1 (z)
  const size_t n_row  = (size_t)(4096 + urz);             // gate 2 (n), 2x dup
  bf16x8 wRZh[8], wRZl[8], wNh[8], wNl[8];
  {
    const bf16* pRZh = WhH + rz_row*2048 + koff;
    const bf16* pRZl = WhL + rz_row*2048 + koff;
    const bf16* pNh  = WhH + n_row*2048 + koff;
    const bf16* pNl  = WhL + n_row*2048 + koff;
#pragma unroll
    for (int c = 0; c < 8; c++) {
      wRZh[c] = *(const bf16x8*)(pRZh + c*32);
      wRZl[c] = *(const bf16x8*)(pRZl + c*32);
      wNh[c]  = *(const bf16x8*)(pNh  + c*32);
      wNl[c]  = *(const bf16x8*)(pNl  + c*32);
    }
  }

  // ---- gate-lane state (waves 0,1; lanes lm<8): unit gu, rows w*16+lk*4+k
  const bool gatelane = (w < 2) && (lm < 8);
  const int gu = u0 + lm;
  float br_ = 0.f, bz_ = 0.f, bn_ = 0.f;
  float hst[4] = {0.f, 0.f, 0.f, 0.f};
  if (gatelane) {
    br_ = bhh[gu]; bz_ = bhh[2048 + gu]; bn_ = bhh[4096 + gu];
    if (t0_abs != 0) {
#pragma unroll
      for (int k = 0; k < 4; k++)
        hst[k] = h32[(size_t)(w*16 + lk*4 + k)*2048 + gu];
    }
  }

#pragma unroll 1
  for (int tt = 0; tt < 32; tt++) {
    const int t = t0_abs + tt;

    // gi prefetch (independent of h; hides under MFMA phase)
    float gv[4][3];
    if (gatelane) {
      const float* git = gi + (size_t)tt*196608;
#pragma unroll
      for (int k = 0; k < 4; k++) {
        const float* gr = git + (size_t)(w*16 + lk*4 + k)*6144 + gu;
        gv[k][0] = gr[0]; gv[k][1] = gr[2048]; gv[k][2] = gr[4096];
      }
    }

    const bf16* aH = (t == 0) ? z16 : XYEhi + (size_t)(t-1)*65536;
    const bf16* aL = (t == 0) ? z16 : XYElo + (size_t)(t-1)*65536;
    const bf16* pa  = aH + (size_t)lm*2048 + koff;
    const bf16* pal = aL + (size_t)lm*2048 + koff;

    f32x4 acc[2][2];
#pragma unroll
    for (int i = 0; i < 2; i++)
#pragma unroll
      for (int j2 = 0; j2 < 2; j2++) acc[i][j2] = (f32x4){0.f,0.f,0.f,0.f};

#pragma unroll
    for (int c = 0; c < 8; c++) {
      bf16x8 ah0 = *(const bf16x8*)(pa  + c*32);
      bf16x8 ah1 = *(const bf16x8*)(pa  + 32768 + c*32);
      bf16x8 al0 = *(const bf16x8*)(pal + c*32);
      bf16x8 al1 = *(const bf16x8*)(pal + 32768 + c*32);
      acc[0][0] = MFMA(ah0, wRZh[c], acc[0][0], 0,0,0);
      acc[0][0] = MFMA(al0, wRZh[c], acc[0][0], 0,0,0);
      acc[0][0] = MFMA(ah0, wRZl[c], acc[0][0], 0,0,0);
      acc[0][1] = MFMA(ah0, wNh[c],  acc[0][1], 0,0,0);
      acc[0][1] = MFMA(al0, wNh[c],  acc[0][1], 0,0,0);
      acc[0][1] = MFMA(ah0, wNl[c],  acc[0][1], 0,0,0);
      acc[1][0] = MFMA(ah1, wRZh[c], acc[1][0], 0,0,0);
      acc[1][0] = MFMA(al1, wRZh[c], acc[1][0], 0,0,0);
      acc[1][0] = MFMA(ah1, wRZl[c], acc[1][0], 0,0,0);
      acc[1][1] = MFMA(ah1, wNh[c],  acc[1][1], 0,0,0);
      acc[1][1] = MFMA(al1, wNh[c],  acc[1][1], 0,0,0);
      acc[1][1] = MFMA(ah1, wNl[c],  acc[1][1], 0,0,0);
    }

    // partials -> LDS  (idx = mt*8 + frag*4 + k)
    float* mr = red + (size_t)(w*64 + l)*17;
#pragma unroll
    for (int mt = 0; mt < 2; mt++)
#pragma unroll
      for (int f = 0; f < 2; f++)
#pragma unroll
        for (int k = 0; k < 4; k++)
          mr[mt*8 + f*4 + k] = acc[mt][f][k];
    __syncthreads();

    // cross-wave reduce into plane 0 (all 512 threads, 2 (lane,idx) pairs each)
#pragma unroll
    for (int j2 = 0; j2 < 2; j2++) {
      int p = tid*2 + j2;
      int lp = p >> 4, idx = p & 15;
      float s = red[lp*17 + idx];
#pragma unroll
      for (int w2 = 1; w2 < 8; w2++) s += red[(w2*64 + lp)*17 + idx];
      red[lp*17 + idx] = s;
    }
    __syncthreads();

    // gates: wave w=mt handles rows mt*16 + lk*4 + k of its 8 units
    if (gatelane) {
      bf16* oHi = XYEhi + (size_t)t*65536;
      bf16* oLo = XYElo + (size_t)t*65536;
#pragma unroll
      for (int k = 0; k < 4; k++) {
        float rsum = red[(lk*16 + lm)*17     + w*8 + k];
        float zsum = red[(lk*16 + lm + 8)*17 + w*8 + k];
        float nsum = red[(lk*16 + lm)*17     + w*8 + 4 + k];
        float rr = sigm(gv[k][0] + rsum + br_);
        float zz = sigm(gv[k][1] + zsum + bz_);
        float nn = tanhf(gv[k][2] + rr*(nsum + bn_));
        float hnew = (1.f - zz)*nn + zz*hst[k];
        hst[k] = hnew;
        bf16 hb = (bf16)hnew;
        size_t idx2 = (size_t)(w*16 + lk*4 + k)*2048 + gu;
        oHi[idx2] = hb;
        oLo[idx2] = (bf16)(hnew - (float)hb);
      }
    }

    // grid barrier (monotone counter; skip after last step — kernel boundary syncs)
    if (tt < 31) {
      __syncthreads();
      if (tid == 0) {
        __threadfence();   // release: drain our h_t stores to device scope
        __hip_atomic_fetch_add(bar, 1u, __ATOMIC_RELAXED, __HIP_MEMORY_SCOPE_AGENT);
        unsigned tgt = bar_base + (unsigned)(tt + 1)*256u;
        while (__hip_atomic_load(bar, __ATOMIC_RELAXED, __HIP_MEMORY_SCOPE_AGENT) < tgt)
          __builtin_amdgcn_s_sleep(2);
        __threadfence();   // acquire: invalidate stale lines before reading h_t
      }
      __syncthreads();
    }
  }

  // phase handoff
  if (gatelane) {
#pragma unroll
    for (int k = 0; k < 4; k++)
      h32[(size_t)(w*16 + lk*4 + k)*2048 + gu] = hst[k];
  }
}

// ---------------- temporal attention (reads emb hi+lo)
__global__ __launch_bounds__(256) void k_attn(
    const bf16* __restrict__ eHi, const bf16* __restrict__ eLo, // (128,32,2048)
    const float* __restrict__ A_w, const float* __restrict__ A_b,
    float* __restrict__ att_vec)    // (128,2048)
{
  __shared__ float Aw[1024];
  __shared__ float Ab[32];
  const int n = blockIdx.x, tid = threadIdx.x;
  for (int i = tid; i < 1024; i += 256) Aw[i] = A_w[i];
  if (tid < 32) Ab[tid] = A_b[tid];
  __syncthreads();
  for (int f = tid; f < 2048; f += 256) {
    float a[32];
#pragma unroll
    for (int t = 0; t < 32; t++) {
      size_t ix = (size_t)n*65536 + t*2048 + f;
      a[t] = tanhf((float)eHi[ix] + (float)eLo[ix]);
    }
    float aw[32]; float mx = -1e30f;
#pragma unroll
    for (int t2 = 0; t2 < 32; t2++) {
      float s = Ab[t2];
#pragma unroll
      for (int t = 0; t < 32; t++) s += Aw[t2*32 + t]*a[t];
      aw[t2] = s; mx = fmaxf(mx, s);
    }
    float den = 0.f, num = 0.f;
#pragma unroll
    for (int t = 0; t < 32; t++) { float e = expf(aw[t]-mx); den += e; num += e*a[t]; }
    att_vec[n*2048 + f] = tanhf(num/den);
  }
}

// ---------------- both GATv2 layers fused (fp32); block = 32-node dense subgraph
__global__ __launch_bounds__(256) void k_gat(
    const float* __restrict__ xn,
    const float* __restrict__ Wl0, const float* __restrict__ bl0,
    const float* __restrict__ Wr0, const float* __restrict__ br0,
    const float* __restrict__ at0, const float* __restrict__ bs0,
    const float* __restrict__ Wl1, const float* __restrict__ bl1,
    const float* __restrict__ Wr1, const float* __restrict__ br1,
    const float* __restrict__ at1, const float* __restrict__ bs1,
    float* __restrict__ gout)
{
  __shared__ float X[32*64];
  __shared__ float G0s[32*64];
  __shared__ float XL[32*65];
  __shared__ float XR[32*65];
  __shared__ float LG[32*32];
  __shared__ float WlT[64*64];
  __shared__ float WrT[64*64];
  __shared__ float attb[64], blb[64], brb[64], bsb[64];

  const int b = blockIdx.x, tid = threadIdx.x;
  for (int i = tid; i < 2048; i += 256) X[i] = xn[b*2048 + i];

  for (int lay = 0; lay < 2; lay++) {
    const float* Wl = lay ? Wl1 : Wl0;
    const float* Wr = lay ? Wr1 : Wr0;
    const float* bl = lay ? bl1 : bl0;
    const float* br = lay ? br1 : br0;
    const float* at = lay ? at1 : at0;
    const float* bs = lay ? bs1 : bs0;
    __syncthreads();
    for (int i = tid; i < 4096; i += 256) {
      int c = i >> 6, k = i & 63;
      WlT[k*64 + c] = Wl[i];
      WrT[k*64 + c] = Wr[i];
    }
    if (tid < 64) {
      attb[tid] = at[tid]; blb[tid] = bl[tid];
      brb[tid]  = br[tid]; bsb[tid] = bs[tid];
    }
    __syncthreads();
    const float* Xin = lay ? G0s : X;
    for (int e = tid; e < 2048; e += 256) {
      int i = e >> 6, c = e & 63;
      float sl = blb[c], sr = brb[c];
#pragma unroll 8
      for (int k = 0; k < 64; k++) {
        float xv = Xin[i*64 + k];
        sl += xv*WlT[k*64 + c];
        sr += xv*WrT[k*64 + c];
      }
      XL[i*65 + c] = sl; XR[i*65 + c] = sr;
    }
    __syncthreads();
    for (int p = tid; p < 1024; p += 256) {
      int i = p >> 5, j = p & 31;
      float s = 0.f;
#pragma unroll 8
      for (int c = 0; c < 64; c++) {
        float v = XL[i*65 + c] + XR[j*65 + c];
        v = (v > 0.f) ? v : 0.2f*v;
        s += v*attb[c];
      }
      LG[i*32 + j] = s;
    }
    __syncthreads();
    if (tid < 32) {
      int j = tid;
      float m = -1e30f;
      for (int i = 0; i < 32; i++) m = fmaxf(m, LG[i*32 + j]);
      float den = 0.f;
      for (int i = 0; i < 32; i++) den += expf(LG[i*32 + j] - m);
      float inv = 1.f/den;
      for (int i = 0; i < 32; i++) LG[i*32 + j] = expf(LG[i*32 + j] - m)*inv;
    }
    __syncthreads();
    for (int e = tid; e < 2048; e += 256) {
      int j = e >> 6, c = e & 63;
      float s = 0.f;
#pragma unroll 8
      for (int i = 0; i < 32; i++) s += LG[i*32 + j]*XL[i*65 + c];
      float val = tanhf(s + bsb[c]);
      if (lay == 0) G0s[j*64 + c] = val;
      else          gout[b*2048 + j*64 + c] = G0s[j*64 + c] + val;
    }
  }
}

// ---------------- priors[n,o,c,l] = sum_i W_caps[o,l,i]*fusion[n,c,i]
__global__ __launch_bounds__(256) void k_priors(
    const float* __restrict__ att_vec,
    const float* __restrict__ g,
    const float* __restrict__ W_caps,   // (32,64,128)
    float* __restrict__ priors)         // (128,32,32,64)
{
  __shared__ float FU[32*128];
  const int n = blockIdx.x >> 1, oh = blockIdx.x & 1, tid = threadIdx.x;
  for (int e = tid; e < 4096; e += 256) {
    int c = e >> 7, i = e & 127;
    FU[e] = (i < 64) ? att_vec[n*2048 + c*64 + i] : g[n*2048 + c*64 + (i - 64)];
  }
  __syncthreads();
  for (int oo = 0; oo < 16; oo++) {
    int o = oh*16 + oo;
    const float* W = W_caps + (size_t)o*8192;
    for (int e = tid; e < 2048; e += 256) {
      int c = e >> 6, l2 = e & 63;
      const float* Wr_ = W + l2*128;
      float s = 0.f;
#pragma unroll
      for (int i = 0; i < 128; i += 4) {
        float4 w4 = *(const float4*)(Wr_ + i);
        s += w4.x*FU[c*128 + i]     + w4.y*FU[c*128 + i + 1]
           + w4.z*FU[c*128 + i + 2] + w4.w*FU[c*128 + i + 3];
      }
      priors[(((size_t)n*32 + o)*32 + c)*64 + l2] = s;
    }
  }
}

// ---------------- dynamic routing (3 iters) + final FC
__global__ __launch_bounds__(64) void k_route(
    const float* __restrict__ priors,
    const float* __restrict__ F_w, const float* __restrict__ F_b,
    float* __restrict__ out)           // (128,32,32)
{
  __shared__ float ct[2048];
  __shared__ float fwt[2048];
  __shared__ float fbs[32];
  const int n = blockIdx.x, l = threadIdx.x;
  for (int i = l; i < 2048; i += 64) { int d2 = i >> 6, k = i & 63; fwt[k*32 + d2] = F_w[i]; }
  if (l < 32) fbs[l] = F_b[l];
  const float* PR = priors + (size_t)n*65536;

  float S[32];
#pragma unroll
  for (int o = 0; o < 32; o++) S[o] = 0.f;
  for (int c = 0; c < 32; c++) {
#pragma unroll
    for (int o = 0; o < 32; o++) S[o] += PR[(o*32 + c)*64 + l];
  }
#pragma unroll
  for (int o = 0; o < 32; o++) S[o] *= 0.03125f;

  float On[32];
  for (int rr = 0; rr < 2; rr++) {
#pragma unroll
    for (int o = 0; o < 32; o++) On[o] = 0.f;
    for (int c = 0; c < 32; c++) {
      float col[32], eo[32];
      float mx = -1e30f;
#pragma unroll
      for (int o = 0; o < 32; o++) {
        col[o] = PR[(o*32 + c)*64 + l];
        float t = col[o]*S[o];
        eo[o] = t; mx = fmaxf(mx, t);
      }
      float den = 0.f;
#pragma unroll
      for (int o = 0; o < 32; o++) { eo[o] = expf(eo[o]-mx); den += eo[o]; }
      float inv = 1.f/den;
#pragma unroll
      for (int o = 0; o < 32; o++) On[o] += eo[o]*inv*col[o];
    }
    if (rr == 0) {
#pragma unroll
      for (int o = 0; o < 32; o++) S[o] += On[o];
    }
  }
#pragma unroll
  for (int o = 0; o < 32; o++) ct[o*64 + l] = tanhf(On[o]);
  __syncthreads();
#pragma unroll
  for (int e = 0; e < 16; e++) {
    int el = l + e*64;
    int o = el >> 5, d2 = el & 31;
    float s = fbs[d2];
#pragma unroll
    for (int k = 0; k < 64; k++) s += ct[o*64 + k]*fwt[k*32 + d2];
    out[(size_t)n*1024 + el] = tanhf(s);
  }
}

// =====================================================================
extern "C" void kernel_launch(void* const* d_in, const int* in_sizes, int n_in,
                              void* d_out, int out_size, void* d_ws, size_t ws_size,
                              hipStream_t stream) {
  const float* inputs = (const float*)d_in[0];
  const float* Wih0 = (const float*)d_in[1];
  const float* Whh0 = (const float*)d_in[2];
  const float* bih0 = (const float*)d_in[3];
  const float* bhh0 = (const float*)d_in[4];
  const float* Wih1 = (const float*)d_in[5];
  const float* Whh1 = (const float*)d_in[6];
  const float* bih1 = (const float*)d_in[7];
  const float* bhh1 = (const float*)d_in[8];
  const float* A_w  = (const float*)d_in[9];
  const float* A_b  = (const float*)d_in[10];
  const float* g0_Wl = (const float*)d_in[11];
  const float* g0_bl = (const float*)d_in[12];
  const float* g0_Wr = (const float*)d_in[13];
  const float* g0_br = (const float*)d_in[14];
  const float* g0_at = (const float*)d_in[15];
  const float* g0_bs = (const float*)d_in[16];
  const float* g1_Wl = (const float*)d_in[17];
  const float* g1_bl = (const float*)d_in[18];
  const float* g1_Wr = (const float*)d_in[19];
  const float* g1_br = (const float*)d_in[20];
  const float* g1_at = (const float*)d_in[21];
  const float* g1_bs = (const float*)d_in[22];
  const float* W_caps = (const float*)d_in[23];
  const float* F_w  = (const float*)d_in[24];
  const float* F_b  = (const float*)d_in[25];
  // d_in[26] = edge_index: block-dense, not needed.

  char* ws = (char*)d_ws;
  bf16*  WihH  = (bf16*) (ws + 0);
  bf16*  WihL  = (bf16*) (ws + 25165824);
  bf16*  WhhH  = (bf16*) (ws + 50331648);
  bf16*  WhhL  = (bf16*) (ws + 75497472);
  float* gi    = (float*)(ws + 100663296);
  bf16*  XYEhi = (bf16*) (ws + 125829120);
  bf16*  XYElo = (bf16*) (ws + 142606336);
  float* h32   = (float*)(ws + 159383552);
  bf16*  z16   = (bf16*) (ws + 159645696);
  float* attv  = (float*)(ws + 159776768);
  float* g     = (float*)(ws + 160825344);
  float* priors= (float*)(ws + 0);          // overlaps Wih pair (dead at tail)
  unsigned* bar = (unsigned*)(ws + 160825344); // overlaps gbuf (dead until k_gat)

  dim3 gemm_grid(48, 8);   // N=6144/128, M=1024/128

  hipMemsetAsync(z16, 0, 131072, stream);
  hipMemsetAsync(bar, 0, 4, stream);
  k_prep<<<8192, 256, 0, stream>>>((const float4*)inputs, (bf16x4*)XYEhi, (bf16x4*)XYElo, 2097152);

  unsigned bb = 0;
  for (int layer = 0; layer < 2; layer++) {
    const float* Wih = layer ? Wih1 : Wih0;
    const float* Whh = layer ? Whh1 : Whh0;
    const float* bih = layer ? bih1 : bih0;
    const float* bhh = layer ? bhh1 : bhh0;

    k_split<<<12288, 256, 0, stream>>>((const float4*)Wih, (bf16x4*)WihH, (bf16x4*)WihL, 3145728);
    k_split<<<12288, 256, 0, stream>>>((const float4*)Whh, (bf16x4*)WhhH, (bf16x4*)WhhL, 3145728);

    for (int p = 0; p < 4; p++) {
      k_gemm3<<<gemm_grid, 256, 0, stream>>>(
          XYEhi + (size_t)p*1024*2048, XYElo + (size_t)p*1024*2048,
          WihH, WihL, bih, gi, 1024, 6144, 2048);
      k_gru_phase<<<256, 512, 0, stream>>>(WhhH, WhhL, bhh, gi, h32,
          XYEhi, XYElo, z16, p*32, bar, bb);
      bb += 31u*256u;
    }
  }

  // ---- tail (emb == XYE pair)
  k_attn<<<128, 256, 0, stream>>>(XYEhi, XYElo, A_w, A_b, attv);
  k_gat<<<128, 256, 0, stream>>>(attv,
      g0_Wl, g0_bl, g0_Wr, g0_br, g0_at, g0_bs,
      g1_Wl, g1_bl, g1_Wr, g1_br, g1_at, g1_bs, g);
  k_priors<<<256, 256, 0, stream>>>(attv, g, W_caps, priors);
  k_route<<<128, 64, 0, stream>>>(priors, F_w, F_b, (float*)d_out);
}

// Round 3
// 5027.222 us; speedup vs baseline: 1.6831x; 1.5287x over previous
//
#include <hip/hip_runtime.h>
#include <hip/hip_bf16.h>
#include <math.h>

// Dims: D=32, T=32, H=64, B=128, F=2048, 3F=6144, N=4096.
// Scan over axis 0 (128 sequential steps), state (32,2048). All I/O fp32.
// Round-7: round-6 persistent-phase design + crash fix: early-clobber ("=&v")
// on the async global_load_dwordx4 asm outputs. Without it the allocator may
// overlap a load's destination quad with a later load's address pair in the
// same asm block; the async dest-write then corrupts the address -> fault.
//   - h exchange: writes staged in LDS, wave 0 stores 64x16B with sc0 sc1;
//     reads are asm global_load_dwordx4 sc0 sc1, 2-deep pipelined, counted
//     vmcnt + sched_barrier(0) (rule 18).
//   - barrier: tid0 vmcnt(0) (wave 0 holds ALL exchange stores) -> relaxed
//     agent atomic add -> s_sleep(8) spin. Monotone counter in gbuf head.
//   - weights pinned in VGPRs via asm "+v" after load (32 x bf16x8 = 128 VGPR).
//   - NO __threadfence anywhere in the step loop (no L2 wb/inv, no memory
//     clobber => weights stay register-resident).
//
// Workspace (bytes), total 161,873,920 (~154 MB):
//   WihH  [0,          25165824)  bf16 hi
//   WihL  [25165824,   50331648)  bf16 lo
//   WhhH  [50331648,   75497472)
//   WhhL  [75497472,  100663296)
//   gi    [100663296, 125829120)  fp32 (1024,6144) per 32-step phase
//   XYEhi [125829120, 142606336)  bf16 (4096,2048): X -> ys0 -> emb
//   XYElo [142606336, 159383552)
//   h32   [159383552, 159645696)  fp32 (32,2048) phase handoff
//   z16   [159645696, 159776768)  bf16 zeros (t=0 state)
//   attv  [159776768, 160825344)  fp32 (128,2048)
//   gbuf  [160825344, 161873920)  fp32 (128,2048); first 4 B = barrier counter
//   priors[0, 33554432) fp32 — overlaps Wih pair (dead at tail)

typedef __bf16 bf16;
typedef __attribute__((ext_vector_type(4))) __bf16 bf16x4;
typedef __attribute__((ext_vector_type(8))) __bf16 bf16x8;
typedef __attribute__((ext_vector_type(4))) float f32x4;

#define AS1 __attribute__((address_space(1)))
#define AS3 __attribute__((address_space(3)))

__device__ __forceinline__ void gll16(const void* g, void* s) {
  __builtin_amdgcn_global_load_lds((const AS1 void*)g, (AS3 void*)s, 16, 0, 0);
}
__device__ __forceinline__ float sigm(float x) { return 1.0f/(1.0f + expf(-x)); }
#define MFMA __builtin_amdgcn_mfma_f32_16x16x32_bf16

// coherent (device-scope, cache-bypassing) 16B load/store.
// "=&v" early-clobber is REQUIRED: global_load writes dest asynchronously,
// so dest tuples must not alias any address-pair input of the same block.
__device__ __forceinline__ void ldg4_coh(bf16x8& a, bf16x8& b, bf16x8& c, bf16x8& d,
                                         const bf16* pa, const bf16* pb,
                                         const bf16* pc, const bf16* pd) {
  asm volatile("global_load_dwordx4 %0, %4, off sc0 sc1\n\t"
               "global_load_dwordx4 %1, %5, off sc0 sc1\n\t"
               "global_load_dwordx4 %2, %6, off sc0 sc1\n\t"
               "global_load_dwordx4 %3, %7, off sc0 sc1"
               : "=&v"(a), "=&v"(b), "=&v"(c), "=&v"(d)
               : "v"(pa), "v"(pb), "v"(pc), "v"(pd));
}
__device__ __forceinline__ void st_coh16(bf16* p, bf16x8 v) {
  asm volatile("global_store_dwordx4 %0, %1, off sc0 sc1" :: "v"(p), "v"(v));
}
__device__ __forceinline__ void pinv(bf16x8& v) { asm volatile("" : "+v"(v)); }

// ---------------- fp32 -> (hi, lo) bf16 split
__global__ __launch_bounds__(256) void k_split(const float4* __restrict__ in,
                                               bf16x4* __restrict__ hi,
                                               bf16x4* __restrict__ lo, int nvec) {
  int i = blockIdx.x*256 + threadIdx.x;
  if (i >= nvec) return;
  float4 v = in[i];
  bf16x4 h, l;
  h[0]=(bf16)v.x; l[0]=(bf16)(v.x-(float)h[0]);
  h[1]=(bf16)v.y; l[1]=(bf16)(v.y-(float)h[1]);
  h[2]=(bf16)v.z; l[2]=(bf16)(v.z-(float)h[2]);
  h[3]=(bf16)v.w; l[3]=(bf16)(v.w-(float)h[3]);
  hi[i] = h; lo[i] = l;
}

// ---------------- nan_to_num + split
__device__ __forceinline__ float fixv(float x) {
  if (isnan(x)) return 0.f;
  if (isinf(x)) return (x > 0.f) ? 1.0f : -3.4028234663852886e38f;
  return x;
}
__global__ __launch_bounds__(256) void k_prep(const float4* __restrict__ in,
                                              bf16x4* __restrict__ hi,
                                              bf16x4* __restrict__ lo, int nvec) {
  int i = blockIdx.x*256 + threadIdx.x;
  if (i >= nvec) return;
  float4 v = in[i];
  v.x = fixv(v.x); v.y = fixv(v.y); v.z = fixv(v.z); v.w = fixv(v.w);
  bf16x4 h, l;
  h[0]=(bf16)v.x; l[0]=(bf16)(v.x-(float)h[0]);
  h[1]=(bf16)v.y; l[1]=(bf16)(v.y-(float)h[1]);
  h[2]=(bf16)v.z; l[2]=(bf16)(v.z-(float)h[2]);
  h[3]=(bf16)v.w; l[3]=(bf16)(v.w-(float)h[3]);
  hi[i] = h; lo[i] = l;
}

// ---------------- C(M,N) fp32 = (Ah+Al)(M,K) @ (Bh+Bl)(N,K)^T + bias
// 3-term split-precision MFMA: AhBh + AlBh + AhBl. 128x128 tile, 4 waves, BK=64.
__global__ __launch_bounds__(256) void k_gemm3(
    const bf16* __restrict__ Ah, const bf16* __restrict__ Al,
    const bf16* __restrict__ Bh, const bf16* __restrict__ Bl,
    const float* __restrict__ bias, float* __restrict__ C,
    int M, int N, int K)
{
  __shared__ bf16x8 AsH[1024], AsL[1024], BsH[1024], BsL[1024];
  const int tid = threadIdx.x;
  const int w = tid >> 6, l = tid & 63;
  const int lm = l & 15, lk = l >> 4;
  const int m0 = blockIdx.y * 128, n0 = blockIdx.x * 128;
  const int wm = w & 1, wn = w >> 1;

  f32x4 acc[4][4];
#pragma unroll
  for (int i = 0; i < 4; i++)
#pragma unroll
    for (int j = 0; j < 4; j++) acc[i][j] = (f32x4){0.f,0.f,0.f,0.f};

  const int row_s = (w*64 + l) >> 3;
  const int s_s   = l & 7;

  for (int k0 = 0; k0 < K; k0 += 64) {
#pragma unroll
    for (int q = 0; q < 4; q++) {
      int row = q*32 + row_s;
      size_t offA = (size_t)(m0+row)*K + k0 + s_s*8;
      size_t offB = (size_t)(n0+row)*K + k0 + s_s*8;
      gll16(Ah + offA, &AsH[q*256 + w*64]);
      gll16(Al + offA, &AsL[q*256 + w*64]);
      gll16(Bh + offB, &BsH[q*256 + w*64]);
      gll16(Bl + offB, &BsL[q*256 + w*64]);
    }
    __syncthreads();
#pragma unroll
    for (int ko = 0; ko < 2; ko++) {
      const int kgl = ko*4 + lk;
      bf16x8 aFh[4], aFl[4], bFh[4], bFl[4];
#pragma unroll
      for (int mt = 0; mt < 4; mt++) {
        int r = (wm*64 + mt*16 + lm)*8 + kgl;
        aFh[mt] = AsH[r]; aFl[mt] = AsL[r];
      }
#pragma unroll
      for (int nt = 0; nt < 4; nt++) {
        int r = (wn*64 + nt*16 + lm)*8 + kgl;
        bFh[nt] = BsH[r]; bFl[nt] = BsL[r];
      }
#pragma unroll
      for (int mt = 0; mt < 4; mt++)
#pragma unroll
        for (int nt = 0; nt < 4; nt++) {
          acc[mt][nt] = MFMA(aFh[mt], bFh[nt], acc[mt][nt], 0,0,0);
          acc[mt][nt] = MFMA(aFl[mt], bFh[nt], acc[mt][nt], 0,0,0);
          acc[mt][nt] = MFMA(aFh[mt], bFl[nt], acc[mt][nt], 0,0,0);
        }
    }
    __syncthreads();
  }

  // C/D: col = lane&15, row = (lane>>4)*4 + reg
#pragma unroll
  for (int nt = 0; nt < 4; nt++) {
    int col = n0 + wn*64 + nt*16 + lm;
    float bv = bias[col];
#pragma unroll
    for (int mt = 0; mt < 4; mt++) {
      int rowb = m0 + wm*64 + mt*16 + lk*4;
#pragma unroll
      for (int r = 0; r < 4; r++)
        C[(size_t)(rowb + r)*N + col] = acc[mt][nt][r] + bv;
    }
  }
}

// ---------------- persistent GRU phase: 32 steps in one kernel.
// 256 blocks x 512 threads (8 waves, 2/SIMD, 256-VGPR cap). Block owns 8 units.
// Wave w covers K-slice [w*256,+256); Whh hi/lo fragments pinned in VGPRs
// (32 x bf16x8 = 128 VGPR/lane) across all 32 steps.
// Per step: coherent h loads (sc0 sc1, 2-deep pipelined, counted vmcnt) ->
// 3-term MFMA -> LDS cross-wave reduce -> waves 0/1 gates (h in regs) ->
// h_t staged in LDS -> wave 0 stores 64x16B sc0 sc1 -> tid0 vmcnt(0) +
// relaxed agent atomic barrier (monotone counter) -> next step.
__global__ __launch_bounds__(512, 2) void k_gru_phase(
    const bf16* __restrict__ WhH, const bf16* __restrict__ WhL,  // (6144,2048)
    const float* __restrict__ bhh,
    const float* __restrict__ gi,     // (1024,6144) fp32 for this phase (incl bih)
    float* __restrict__ h32,          // (32,2048) fp32 phase handoff
    bf16* XYEhi, bf16* XYElo,         // full (4096,2048) buffers (read t-1, write t)
    const bf16* __restrict__ z16,     // zeros for t==0
    int t0_abs, unsigned* bar, unsigned bar_base)
{
  __shared__ float red[8704];         // [8 waves][64 lanes][17]
  __shared__ bf16 hstgH[32][8], hstgL[32][8];
  const int tid = threadIdx.x;
  const int w = tid >> 6, l = tid & 63;
  const int lm = l & 15, lk = l >> 4;
  const int u0 = blockIdx.x * 8;

  // ---- weight fragments, loaded once, pinned in regs for all 32 steps
  const size_t koff = (size_t)(w*256 + lk*8);
  const int urz = u0 + (lm & 7);
  const size_t rz_row = (size_t)((lm >> 3)*2048 + urz);   // gate 0 (r) or 1 (z)
  const size_t n_row  = (size_t)(4096 + urz);             // gate 2 (n), 2x dup
  bf16x8 wRZh[8], wRZl[8], wNh[8], wNl[8];
  {
    const bf16* pRZh = WhH + rz_row*2048 + koff;
    const bf16* pRZl = WhL + rz_row*2048 + koff;
    const bf16* pNh  = WhH + n_row*2048 + koff;
    const bf16* pNl  = WhL + n_row*2048 + koff;
#pragma unroll
    for (int c = 0; c < 8; c++) {
      wRZh[c] = *(const bf16x8*)(pRZh + c*32);
      wRZl[c] = *(const bf16x8*)(pRZl + c*32);
      wNh[c]  = *(const bf16x8*)(pNh  + c*32);
      wNl[c]  = *(const bf16x8*)(pNl  + c*32);
    }
#pragma unroll
    for (int c = 0; c < 8; c++) { pinv(wRZh[c]); pinv(wRZl[c]); pinv(wNh[c]); pinv(wNl[c]); }
  }

  // ---- gate-lane state (waves 0,1; lanes lm<8): unit gu, rows w*16+lk*4+k
  const bool gatelane = (w < 2) && (lm < 8);
  const int gu = u0 + lm;
  float br_ = 0.f, bz_ = 0.f, bn_ = 0.f;
  float hst[4] = {0.f, 0.f, 0.f, 0.f};
  if (gatelane) {
    br_ = bhh[gu]; bz_ = bhh[2048 + gu]; bn_ = bhh[4096 + gu];
    if (t0_abs != 0) {
#pragma unroll
      for (int k = 0; k < 4; k++)
        hst[k] = h32[(size_t)(w*16 + lk*4 + k)*2048 + gu];
    }
  }

#define GRU_MFMA(c, CUR)                                              \
  acc[0][0] = MFMA(CUR[0], wRZh[c], acc[0][0], 0,0,0);                \
  acc[0][0] = MFMA(CUR[2], wRZh[c], acc[0][0], 0,0,0);                \
  acc[0][0] = MFMA(CUR[0], wRZl[c], acc[0][0], 0,0,0);                \
  acc[0][1] = MFMA(CUR[0], wNh[c],  acc[0][1], 0,0,0);                \
  acc[0][1] = MFMA(CUR[2], wNh[c],  acc[0][1], 0,0,0);                \
  acc[0][1] = MFMA(CUR[0], wNl[c],  acc[0][1], 0,0,0);                \
  acc[1][0] = MFMA(CUR[1], wRZh[c], acc[1][0], 0,0,0);                \
  acc[1][0] = MFMA(CUR[3], wRZh[c], acc[1][0], 0,0,0);                \
  acc[1][0] = MFMA(CUR[1], wRZl[c], acc[1][0], 0,0,0);                \
  acc[1][1] = MFMA(CUR[1], wNh[c],  acc[1][1], 0,0,0);                \
  acc[1][1] = MFMA(CUR[3], wNh[c],  acc[1][1], 0,0,0);                \
  acc[1][1] = MFMA(CUR[1], wNl[c],  acc[1][1], 0,0,0);

#define KSTEP(c, CUR, NXT)                                            \
  {                                                                   \
    const bf16* q  = pa  + (c+1)*32;                                  \
    const bf16* ql = pal + (c+1)*32;                                  \
    ldg4_coh(NXT[0], NXT[1], NXT[2], NXT[3], q, q + 32768, ql, ql + 32768); \
    asm volatile("s_waitcnt vmcnt(4)");                               \
    __builtin_amdgcn_sched_barrier(0);                                \
    GRU_MFMA(c, CUR)                                                  \
  }
#define KLAST(c, CUR)                                                 \
  {                                                                   \
    asm volatile("s_waitcnt vmcnt(0)");                               \
    __builtin_amdgcn_sched_barrier(0);                                \
    GRU_MFMA(c, CUR)                                                  \
  }

#pragma unroll 1
  for (int tt = 0; tt < 32; tt++) {
    const int t = t0_abs + tt;

    // gi prefetch (independent of h; hides under MFMA phase)
    float gv[4][3];
    if (gatelane) {
      const float* git = gi + (size_t)tt*196608;
#pragma unroll
      for (int k = 0; k < 4; k++) {
        const float* gr = git + (size_t)(w*16 + lk*4 + k)*6144 + gu;
        gv[k][0] = gr[0]; gv[k][1] = gr[2048]; gv[k][2] = gr[4096];
      }
    }

    const bf16* aH = (t == 0) ? z16 : XYEhi + (size_t)(t-1)*65536;
    const bf16* aL = (t == 0) ? z16 : XYElo + (size_t)(t-1)*65536;
    const bf16* pa  = aH + (size_t)lm*2048 + koff;
    const bf16* pal = aL + (size_t)lm*2048 + koff;

    f32x4 acc[2][2];
#pragma unroll
    for (int i = 0; i < 2; i++)
#pragma unroll
      for (int j2 = 0; j2 < 2; j2++) acc[i][j2] = (f32x4){0.f,0.f,0.f,0.f};

    bf16x8 g0[4], g1[4];
    ldg4_coh(g0[0], g0[1], g0[2], g0[3], pa, pa + 32768, pal, pal + 32768);
    KSTEP(0, g0, g1) KSTEP(1, g1, g0) KSTEP(2, g0, g1) KSTEP(3, g1, g0)
    KSTEP(4, g0, g1) KSTEP(5, g1, g0) KSTEP(6, g0, g1) KLAST(7, g1)

    // partials -> LDS  (idx = mt*8 + frag*4 + k)
    float* mr = red + (size_t)(w*64 + l)*17;
#pragma unroll
    for (int mt = 0; mt < 2; mt++)
#pragma unroll
      for (int f = 0; f < 2; f++)
#pragma unroll
        for (int k = 0; k < 4; k++)
          mr[mt*8 + f*4 + k] = acc[mt][f][k];
    __syncthreads();

    // cross-wave reduce into plane 0 (all 512 threads, 2 (lane,idx) pairs each)
#pragma unroll
    for (int j2 = 0; j2 < 2; j2++) {
      int p = tid*2 + j2;
      int lp = p >> 4, idx = p & 15;
      float s = red[lp*17 + idx];
#pragma unroll
      for (int w2 = 1; w2 < 8; w2++) s += red[(w2*64 + lp)*17 + idx];
      red[lp*17 + idx] = s;
    }
    __syncthreads();

    // gates: wave w=mt handles rows mt*16 + lk*4 + k of its 8 units
    if (gatelane) {
#pragma unroll
      for (int k = 0; k < 4; k++) {
        float rsum = red[(lk*16 + lm)*17     + w*8 + k];
        float zsum = red[(lk*16 + lm + 8)*17 + w*8 + k];
        float nsum = red[(lk*16 + lm)*17     + w*8 + 4 + k];
        float rr = sigm(gv[k][0] + rsum + br_);
        float zz = sigm(gv[k][1] + zsum + bz_);
        float nn = tanhf(gv[k][2] + rr*(nsum + bn_));
        float hnew = (1.f - zz)*nn + zz*hst[k];
        hst[k] = hnew;
        bf16 hb = (bf16)hnew;
        int row = w*16 + lk*4 + k;
        hstgH[row][lm] = hb;
        hstgL[row][lm] = (bf16)(hnew - (float)hb);
      }
    }
    __syncthreads();   // hstg ready

    // wave 0: coherent 16B stores of this block's h_t columns (hi + lo)
    if (tid < 64) {
      int row = tid >> 1, hf = tid & 1;
      bf16x8 v = hf ? *(const bf16x8*)&hstgL[row][0] : *(const bf16x8*)&hstgH[row][0];
      bf16* dst = (hf ? XYElo : XYEhi) + (size_t)t*65536 + (size_t)row*2048 + u0;
      st_coh16(dst, v);
    }

    // grid barrier (monotone counter; all exchange stores live in wave 0,
    // so tid0's vmcnt(0) is a complete release)
    if (tt < 31) {
      if (tid == 0) {
        asm volatile("s_waitcnt vmcnt(0)");
        __hip_atomic_fetch_add(bar, 1u, __ATOMIC_RELAXED, __HIP_MEMORY_SCOPE_AGENT);
        unsigned tgt = bar_base + (unsigned)(tt + 1)*256u;
        while (__hip_atomic_load(bar, __ATOMIC_RELAXED, __HIP_MEMORY_SCOPE_AGENT) < tgt)
          __builtin_amdgcn_s_sleep(8);
      }
      __syncthreads();
    }
  }

  // drain last step's exchange stores before endpgm
  if (tid < 64) asm volatile("s_waitcnt vmcnt(0)");

  // phase handoff
  if (gatelane) {
#pragma unroll
    for (int k = 0; k < 4; k++)
      h32[(size_t)(w*16 + lk*4 + k)*2048 + gu] = hst[k];
  }
#undef GRU_MFMA
#undef KSTEP
#undef KLAST
}

// ---------------- temporal attention (reads emb hi+lo)
__global__ __launch_bounds__(256) void k_attn(
    const bf16* __restrict__ eHi, const bf16* __restrict__ eLo, // (128,32,2048)
    const float* __restrict__ A_w, const float* __restrict__ A_b,
    float* __restrict__ att_vec)    // (128,2048)
{
  __shared__ float Aw[1024];
  __shared__ float Ab[32];
  const int n = blockIdx.x, tid = threadIdx.x;
  for (int i = tid; i < 1024; i += 256) Aw[i] = A_w[i];
  if (tid < 32) Ab[tid] = A_b[tid];
  __syncthreads();
  for (int f = tid; f < 2048; f += 256) {
    float a[32];
#pragma unroll
    for (int t = 0; t < 32; t++) {
      size_t ix = (size_t)n*65536 + t*2048 + f;
      a[t] = tanhf((float)eHi[ix] + (float)eLo[ix]);
    }
    float aw[32]; float mx = -1e30f;
#pragma unroll
    for (int t2 = 0; t2 < 32; t2++) {
      float s = Ab[t2];
#pragma unroll
      for (int t = 0; t < 32; t++) s += Aw[t2*32 + t]*a[t];
      aw[t2] = s; mx = fmaxf(mx, s);
    }
    float den = 0.f, num = 0.f;
#pragma unroll
    for (int t = 0; t < 32; t++) { float e = expf(aw[t]-mx); den += e; num += e*a[t]; }
    att_vec[n*2048 + f] = tanhf(num/den);
  }
}

// ---------------- both GATv2 layers fused (fp32); block = 32-node dense subgraph
__global__ __launch_bounds__(256) void k_gat(
    const float* __restrict__ xn,
    const float* __restrict__ Wl0, const float* __restrict__ bl0,
    const float* __restrict__ Wr0, const float* __restrict__ br0,
    const float* __restrict__ at0, const float* __restrict__ bs0,
    const float* __restrict__ Wl1, const float* __restrict__ bl1,
    const float* __restrict__ Wr1, const float* __restrict__ br1,
    const float* __restrict__ at1, const float* __restrict__ bs1,
    float* __restrict__ gout)
{
  __shared__ float X[32*64];
  __shared__ float G0s[32*64];
  __shared__ float XL[32*65];
  __shared__ float XR[32*65];
  __shared__ float LG[32*32];
  __shared__ float WlT[64*64];
  __shared__ float WrT[64*64];
  __shared__ float attb[64], blb[64], brb[64], bsb[64];

  const int b = blockIdx.x, tid = threadIdx.x;
  for (int i = tid; i < 2048; i += 256) X[i] = xn[b*2048 + i];

  for (int lay = 0; lay < 2; lay++) {
    const float* Wl = lay ? Wl1 : Wl0;
    const float* Wr = lay ? Wr1 : Wr0;
    const float* bl = lay ? bl1 : bl0;
    const float* br = lay ? br1 : br0;
    const float* at = lay ? at1 : at0;
    const float* bs = lay ? bs1 : bs0;
    __syncthreads();
    for (int i = tid; i < 4096; i += 256) {
      int c = i >> 6, k = i & 63;
      WlT[k*64 + c] = Wl[i];
      WrT[k*64 + c] = Wr[i];
    }
    if (tid < 64) {
      attb[tid] = at[tid]; blb[tid] = bl[tid];
      brb[tid]  = br[tid]; bsb[tid] = bs[tid];
    }
    __syncthreads();
    const float* Xin = lay ? G0s : X;
    for (int e = tid; e < 2048; e += 256) {
      int i = e >> 6, c = e & 63;
      float sl = blb[c], sr = brb[c];
#pragma unroll 8
      for (int k = 0; k < 64; k++) {
        float xv = Xin[i*64 + k];
        sl += xv*WlT[k*64 + c];
        sr += xv*WrT[k*64 + c];
      }
      XL[i*65 + c] = sl; XR[i*65 + c] = sr;
    }
    __syncthreads();
    for (int p = tid; p < 1024; p += 256) {
      int i = p >> 5, j = p & 31;
      float s = 0.f;
#pragma unroll 8
      for (int c = 0; c < 64; c++) {
        float v = XL[i*65 + c] + XR[j*65 + c];
        v = (v > 0.f) ? v : 0.2f*v;
        s += v*attb[c];
      }
      LG[i*32 + j] = s;
    }
    __syncthreads();
    if (tid < 32) {
      int j = tid;
      float m = -1e30f;
      for (int i = 0; i < 32; i++) m = fmaxf(m, LG[i*32 + j]);
      float den = 0.f;
      for (int i = 0; i < 32; i++) den += expf(LG[i*32 + j] - m);
      float inv = 1.f/den;
      for (int i = 0; i < 32; i++) LG[i*32 + j] = expf(LG[i*32 + j] - m)*inv;
    }
    __syncthreads();
    for (int e = tid; e < 2048; e += 256) {
      int j = e >> 6, c = e & 63;
      float s = 0.f;
#pragma unroll 8
      for (int i = 0; i < 32; i++) s += LG[i*32 + j]*XL[i*65 + c];
      float val = tanhf(s + bsb[c]);
      if (lay == 0) G0s[j*64 + c] = val;
      else          gout[b*2048 + j*64 + c] = G0s[j*64 + c] + val;
    }
  }
}

// ---------------- priors[n,o,c,l] = sum_i W_caps[o,l,i]*fusion[n,c,i]
__global__ __launch_bounds__(256) void k_priors(
    const float* __restrict__ att_vec,
    const float* __restrict__ g,
    const float* __restrict__ W_caps,   // (32,64,128)
    float* __restrict__ priors)         // (128,32,32,64)
{
  __shared__ float FU[32*128];
  const int n = blockIdx.x >> 1, oh = blockIdx.x & 1, tid = threadIdx.x;
  for (int e = tid; e < 4096; e += 256) {
    int c = e >> 7, i = e & 127;
    FU[e] = (i < 64) ? att_vec[n*2048 + c*64 + i] : g[n*2048 + c*64 + (i - 64)];
  }
  __syncthreads();
  for (int oo = 0; oo < 16; oo++) {
    int o = oh*16 + oo;
    const float* W = W_caps + (size_t)o*8192;
    for (int e = tid; e < 2048; e += 256) {
      int c = e >> 6, l2 = e & 63;
      const float* Wr_ = W + l2*128;
      float s = 0.f;
#pragma unroll
      for (int i = 0; i < 128; i += 4) {
        float4 w4 = *(const float4*)(Wr_ + i);
        s += w4.x*FU[c*128 + i]     + w4.y*FU[c*128 + i + 1]
           + w4.z*FU[c*128 + i + 2] + w4.w*FU[c*128 + i + 3];
      }
      priors[(((size_t)n*32 + o)*32 + c)*64 + l2] = s;
    }
  }
}

// ---------------- dynamic routing (3 iters) + final FC
__global__ __launch_bounds__(64) void k_route(
    const float* __restrict__ priors,
    const float* __restrict__ F_w, const float* __restrict__ F_b,
    float* __restrict__ out)           // (128,32,32)
{
  __shared__ float ct[2048];
  __shared__ float fwt[2048];
  __shared__ float fbs[32];
  const int n = blockIdx.x, l = threadIdx.x;
  for (int i = l; i < 2048; i += 64) { int d2 = i >> 6, k = i & 63; fwt[k*32 + d2] = F_w[i]; }
  if (l < 32) fbs[l] = F_b[l];
  const float* PR = priors + (size_t)n*65536;

  float S[32];
#pragma unroll
  for (int o = 0; o < 32; o++) S[o] = 0.f;
  for (int c = 0; c < 32; c++) {
#pragma unroll
    for (int o = 0; o < 32; o++) S[o] += PR[(o*32 + c)*64 + l];
  }
#pragma unroll
  for (int o = 0; o < 32; o++) S[o] *= 0.03125f;

  float On[32];
  for (int rr = 0; rr < 2; rr++) {
#pragma unroll
    for (int o = 0; o < 32; o++) On[o] = 0.f;
    for (int c = 0; c < 32; c++) {
      float col[32], eo[32];
      float mx = -1e30f;
#pragma unroll
      for (int o = 0; o < 32; o++) {
        col[o] = PR[(o*32 + c)*64 + l];
        float t = col[o]*S[o];
        eo[o] = t; mx = fmaxf(mx, t);
      }
      float den = 0.f;
#pragma unroll
      for (int o = 0; o < 32; o++) { eo[o] = expf(eo[o]-mx); den += eo[o]; }
      float inv = 1.f/den;
#pragma unroll
      for (int o = 0; o < 32; o++) On[o] += eo[o]*inv*col[o];
    }
    if (rr == 0) {
#pragma unroll
      for (int o = 0; o < 32; o++) S[o] += On[o];
    }
  }
#pragma unroll
  for (int o = 0; o < 32; o++) ct[o*64 + l] = tanhf(On[o]);
  __syncthreads();
#pragma unroll
  for (int e = 0; e < 16; e++) {
    int el = l + e*64;
    int o = el >> 5, d2 = el & 31;
    float s = fbs[d2];
#pragma unroll
    for (int k = 0; k < 64; k++) s += ct[o*64 + k]*fwt[k*32 + d2];
    out[(size_t)n*1024 + el] = tanhf(s);
  }
}

// =====================================================================
extern "C" void kernel_launch(void* const* d_in, const int* in_sizes, int n_in,
                              void* d_out, int out_size, void* d_ws, size_t ws_size,
                              hipStream_t stream) {
  const float* inputs = (const float*)d_in[0];
  const float* Wih0 = (const float*)d_in[1];
  const float* Whh0 = (const float*)d_in[2];
  const float* bih0 = (const float*)d_in[3];
  const float* bhh0 = (const float*)d_in[4];
  const float* Wih1 = (const float*)d_in[5];
  const float* Whh1 = (const float*)d_in[6];
  const float* bih1 = (const float*)d_in[7];
  const float* bhh1 = (const float*)d_in[8];
  const float* A_w  = (const float*)d_in[9];
  const float* A_b  = (const float*)d_in[10];
  const float* g0_Wl = (const float*)d_in[11];
  const float* g0_bl = (const float*)d_in[12];
  const float* g0_Wr = (const float*)d_in[13];
  const float* g0_br = (const float*)d_in[14];
  const float* g0_at = (const float*)d_in[15];
  const float* g0_bs = (const float*)d_in[16];
  const float* g1_Wl = (const float*)d_in[17];
  const float* g1_bl = (const float*)d_in[18];
  const float* g1_Wr = (const float*)d_in[19];
  const float* g1_br = (const float*)d_in[20];
  const float* g1_at = (const float*)d_in[21];
  const float* g1_bs = (const float*)d_in[22];
  const float* W_caps = (const float*)d_in[23];
  const float* F_w  = (const float*)d_in[24];
  const float* F_b  = (const float*)d_in[25];
  // d_in[26] = edge_index: block-dense, not needed.

  char* ws = (char*)d_ws;
  bf16*  WihH  = (bf16*) (ws + 0);
  bf16*  WihL  = (bf16*) (ws + 25165824);
  bf16*  WhhH  = (bf16*) (ws + 50331648);
  bf16*  WhhL  = (bf16*) (ws + 75497472);
  float* gi    = (float*)(ws + 100663296);
  bf16*  XYEhi = (bf16*) (ws + 125829120);
  bf16*  XYElo = (bf16*) (ws + 142606336);
  float* h32   = (float*)(ws + 159383552);
  bf16*  z16   = (bf16*) (ws + 159645696);
  float* attv  = (float*)(ws + 159776768);
  float* g     = (float*)(ws + 160825344);
  float* priors= (float*)(ws + 0);          // overlaps Wih pair (dead at tail)
  unsigned* bar = (unsigned*)(ws + 160825344); // overlaps gbuf (dead until k_gat)

  dim3 gemm_grid(48, 8);   // N=6144/128, M=1024/128

  hipMemsetAsync(z16, 0, 131072, stream);
  hipMemsetAsync(bar, 0, 4, stream);
  k_prep<<<8192, 256, 0, stream>>>((const float4*)inputs, (bf16x4*)XYEhi, (bf16x4*)XYElo, 2097152);

  unsigned bb = 0;
  for (int layer = 0; layer < 2; layer++) {
    const float* Wih = layer ? Wih1 : Wih0;
    const float* Whh = layer ? Whh1 : Whh0;
    const float* bih = layer ? bih1 : bih0;
    const float* bhh = layer ? bhh1 : bhh0;

    k_split<<<12288, 256, 0, stream>>>((const float4*)Wih, (bf16x4*)WihH, (bf16x4*)WihL, 3145728);
    k_split<<<12288, 256, 0, stream>>>((const float4*)Whh, (bf16x4*)WhhH, (bf16x4*)WhhL, 3145728);

    for (int p = 0; p < 4; p++) {
      k_gemm3<<<gemm_grid, 256, 0, stream>>>(
          XYEhi + (size_t)p*1024*2048, XYElo + (size_t)p*1024*2048,
          WihH, WihL, bih, gi, 1024, 6144, 2048);
      k_gru_phase<<<256, 512, 0, stream>>>(WhhH, WhhL, bhh, gi, h32,
          XYEhi, XYElo, z16, p*32, bar, bb);
      bb += 31u*256u;
    }
  }

  // ---- tail (emb == XYE pair)
  k_attn<<<128, 256, 0, stream>>>(XYEhi, XYElo, A_w, A_b, attv);
  k_gat<<<128, 256, 0, stream>>>(attv,
      g0_Wl, g0_bl, g0_Wr, g0_br, g0_at, g0_bs,
      g1_Wl, g1_bl, g1_Wr, g1_br, g1_at, g1_bs, g);
  k_priors<<<256, 256, 0, stream>>>(attv, g, W_caps, priors);
  k_route<<<128, 64, 0, stream>>>(priors, F_w, F_b, (float*)d_out);
}

// Round 6
// 5010.625 us; speedup vs baseline: 1.6887x; 1.0033x over previous
//
#include <hip/hip_runtime.h>
#include <hip/hip_bf16.h>
#include <math.h>

// Dims: D=32, T=32, H=64, B=128, F=2048, 3F=6144, N=4096.
// Scan over axis 0 (128 sequential steps), state (32,2048). All I/O fp32.
// Round-10: revert to round-7 (passing, 5027us) + two minimal deltas:
//   (1) h-exchange LOADS are plain cached (no sc bits). Safe: each exchange
//       address is write-once-then-read-once within the dispatch (t-indexed
//       buffers; kernel-start acquire invalidated L1/L2), and the grid
//       barrier orders the sc0|sc1 write-through stores (L3-visible) before
//       any reader's miss-fill. First toucher per XCD pulls a line to L2;
//       the other 31 blocks hit L2 -> ~32x less L3 traffic per step.
//   (2) weight fragments pinned to AGPRs via asm "+a" (128 AGPRs). Asm
//       results can't be rematerialized; AGPR residency frees the VGPR file
//       (fixes round-3's VGPR_Count=124 < 128 => weights re-streamed).
//   Everything else (MFMA builtins, ping-pong loads, counted vmcnt(4),
//   LDS reduce, gates, barrier) is byte-identical to the passing round-7.
//   absmax must stay exactly 2.441e-4 (identical arithmetic).
//
// Workspace (bytes), total 161,873,920 (~154 MB): layout unchanged.
//   WihH[0) WihL[25165824) WhhH[50331648) WhhL[75497472) gi[100663296)
//   XYEhi[125829120) XYElo[142606336) h32[159383552) z16[159645696)
//   attv[159776768) gbuf[160825344) (bar = gbuf head)  priors overlaps Wih.

typedef __bf16 bf16;
typedef __attribute__((ext_vector_type(4))) __bf16 bf16x4;
typedef __attribute__((ext_vector_type(8))) __bf16 bf16x8;
typedef __attribute__((ext_vector_type(4))) float f32x4;

#define AS1 __attribute__((address_space(1)))
#define AS3 __attribute__((address_space(3)))

__device__ __forceinline__ void gll16(const void* g, void* s) {
  __builtin_amdgcn_global_load_lds((const AS1 void*)g, (AS3 void*)s, 16, 0, 0);
}
__device__ __forceinline__ float sigm(float x) { return 1.0f/(1.0f + expf(-x)); }
#define MFMA __builtin_amdgcn_mfma_f32_16x16x32_bf16

// h-exchange loads: plain cached (see header). "=&v" early-clobber REQUIRED:
// async dest writes must not alias the address-pair inputs of the same block.
__device__ __forceinline__ void ldg4(bf16x8& a, bf16x8& b, bf16x8& c, bf16x8& d,
                                     const bf16* pa, const bf16* pb,
                                     const bf16* pc, const bf16* pd) {
  asm volatile("global_load_dwordx4 %0, %4, off\n\t"
               "global_load_dwordx4 %1, %5, off\n\t"
               "global_load_dwordx4 %2, %6, off\n\t"
               "global_load_dwordx4 %3, %7, off"
               : "=&v"(a), "=&v"(b), "=&v"(c), "=&v"(d)
               : "v"(pa), "v"(pb), "v"(pc), "v"(pd));
}
// exchange stores: write-through to the coherent point (L3)
__device__ __forceinline__ void st_coh16(bf16* p, bf16x8 v) {
  asm volatile("global_store_dwordx4 %0, %1, off sc0 sc1" :: "v"(p), "v"(v));
}
// pin a fragment into AGPRs (not rematerializable; off the VGPR budget)
__device__ __forceinline__ void pina(bf16x8& v) { asm volatile("" : "+a"(v)); }

// ---------------- fp32 -> (hi, lo) bf16 split
__global__ __launch_bounds__(256) void k_split(const float4* __restrict__ in,
                                               bf16x4* __restrict__ hi,
                                               bf16x4* __restrict__ lo, int nvec) {
  int i = blockIdx.x*256 + threadIdx.x;
  if (i >= nvec) return;
  float4 v = in[i];
  bf16x4 h, l;
  h[0]=(bf16)v.x; l[0]=(bf16)(v.x-(float)h[0]);
  h[1]=(bf16)v.y; l[1]=(bf16)(v.y-(float)h[1]);
  h[2]=(bf16)v.z; l[2]=(bf16)(v.z-(float)h[2]);
  h[3]=(bf16)v.w; l[3]=(bf16)(v.w-(float)h[3]);
  hi[i] = h; lo[i] = l;
}

// ---------------- nan_to_num + split
__device__ __forceinline__ float fixv(float x) {
  if (isnan(x)) return 0.f;
  if (isinf(x)) return (x > 0.f) ? 1.0f : -3.4028234663852886e38f;
  return x;
}
__global__ __launch_bounds__(256) void k_prep(const float4* __restrict__ in,
                                              bf16x4* __restrict__ hi,
                                              bf16x4* __restrict__ lo, int nvec) {
  int i = blockIdx.x*256 + threadIdx.x;
  if (i >= nvec) return;
  float4 v = in[i];
  v.x = fixv(v.x); v.y = fixv(v.y); v.z = fixv(v.z); v.w = fixv(v.w);
  bf16x4 h, l;
  h[0]=(bf16)v.x; l[0]=(bf16)(v.x-(float)h[0]);
  h[1]=(bf16)v.y; l[1]=(bf16)(v.y-(float)h[1]);
  h[2]=(bf16)v.z; l[2]=(bf16)(v.z-(float)h[2]);
  h[3]=(bf16)v.w; l[3]=(bf16)(v.w-(float)h[3]);
  hi[i] = h; lo[i] = l;
}

// ---------------- C(M,N) fp32 = (Ah+Al)(M,K) @ (Bh+Bl)(N,K)^T + bias
// 3-term split-precision MFMA: AhBh + AlBh + AhBl. 128x128 tile, 4 waves, BK=64.
__global__ __launch_bounds__(256) void k_gemm3(
    const bf16* __restrict__ Ah, const bf16* __restrict__ Al,
    const bf16* __restrict__ Bh, const bf16* __restrict__ Bl,
    const float* __restrict__ bias, float* __restrict__ C,
    int M, int N, int K)
{
  __shared__ bf16x8 AsH[1024], AsL[1024], BsH[1024], BsL[1024];
  const int tid = threadIdx.x;
  const int w = tid >> 6, l = tid & 63;
  const int lm = l & 15, lk = l >> 4;
  const int m0 = blockIdx.y * 128, n0 = blockIdx.x * 128;
  const int wm = w & 1, wn = w >> 1;

  f32x4 acc[4][4];
#pragma unroll
  for (int i = 0; i < 4; i++)
#pragma unroll
    for (int j = 0; j < 4; j++) acc[i][j] = (f32x4){0.f,0.f,0.f,0.f};

  const int row_s = (w*64 + l) >> 3;
  const int s_s   = l & 7;

  for (int k0 = 0; k0 < K; k0 += 64) {
#pragma unroll
    for (int q = 0; q < 4; q++) {
      int row = q*32 + row_s;
      size_t offA = (size_t)(m0+row)*K + k0 + s_s*8;
      size_t offB = (size_t)(n0+row)*K + k0 + s_s*8;
      gll16(Ah + offA, &AsH[q*256 + w*64]);
      gll16(Al + offA, &AsL[q*256 + w*64]);
      gll16(Bh + offB, &BsH[q*256 + w*64]);
      gll16(Bl + offB, &BsL[q*256 + w*64]);
    }
    __syncthreads();
#pragma unroll
    for (int ko = 0; ko < 2; ko++) {
      const int kgl = ko*4 + lk;
      bf16x8 aFh[4], aFl[4], bFh[4], bFl[4];
#pragma unroll
      for (int mt = 0; mt < 4; mt++) {
        int r = (wm*64 + mt*16 + lm)*8 + kgl;
        aFh[mt] = AsH[r]; aFl[mt] = AsL[r];
      }
#pragma unroll
      for (int nt = 0; nt < 4; nt++) {
        int r = (wn*64 + nt*16 + lm)*8 + kgl;
        bFh[nt] = BsH[r]; bFl[nt] = BsL[r];
      }
#pragma unroll
      for (int mt = 0; mt < 4; mt++)
#pragma unroll
        for (int nt = 0; nt < 4; nt++) {
          acc[mt][nt] = MFMA(aFh[mt], bFh[nt], acc[mt][nt], 0,0,0);
          acc[mt][nt] = MFMA(aFl[mt], bFh[nt], acc[mt][nt], 0,0,0);
          acc[mt][nt] = MFMA(aFh[mt], bFl[nt], acc[mt][nt], 0,0,0);
        }
    }
    __syncthreads();
  }

  // C/D: col = lane&15, row = (lane>>4)*4 + reg
#pragma unroll
  for (int nt = 0; nt < 4; nt++) {
    int col = n0 + wn*64 + nt*16 + lm;
    float bv = bias[col];
#pragma unroll
    for (int mt = 0; mt < 4; mt++) {
      int rowb = m0 + wm*64 + mt*16 + lk*4;
#pragma unroll
      for (int r = 0; r < 4; r++)
        C[(size_t)(rowb + r)*N + col] = acc[mt][nt][r] + bv;
    }
  }
}

// ---------------- persistent GRU phase: 32 steps in one kernel.
// 256 blocks x 512 threads (8 waves, 2/SIMD, 256-unified-reg cap). Block owns
// 8 units. Wave w covers K-slice [w*256,+256); Whh hi/lo fragments pinned in
// AGPRs (32 x bf16x8 = 128 AGPRs) across all 32 steps.
// Per step: cached h loads (2-deep pipelined, counted vmcnt) -> 3-term MFMA
// -> LDS cross-wave reduce -> waves 0/1 gates (h in regs) -> h_t staged in
// LDS -> wave 0 stores 64x16B sc0 sc1 -> tid0 vmcnt(0) + relaxed agent
// atomic barrier (monotone counter) -> next step.
__global__ __launch_bounds__(512, 2) void k_gru_phase(
    const bf16* __restrict__ WhH, const bf16* __restrict__ WhL,  // (6144,2048)
    const float* __restrict__ bhh,
    const float* __restrict__ gi,     // (1024,6144) fp32 for this phase (incl bih)
    float* __restrict__ h32,          // (32,2048) fp32 phase handoff
    bf16* XYEhi, bf16* XYElo,         // full (4096,2048) buffers (read t-1, write t)
    const bf16* __restrict__ z16,     // zeros for t==0
    int t0_abs, unsigned* bar, unsigned bar_base)
{
  __shared__ float red[8704];         // [8 waves][64 lanes][17]
  __shared__ bf16 hstgH[32][8], hstgL[32][8];
  const int tid = threadIdx.x;
  const int w = tid >> 6, l = tid & 63;
  const int lm = l & 15, lk = l >> 4;
  const int u0 = blockIdx.x * 8;

  // ---- weight fragments, loaded once, pinned in AGPRs for all 32 steps
  const size_t koff = (size_t)(w*256 + lk*8);
  const int urz = u0 + (lm & 7);
  const size_t rz_row = (size_t)((lm >> 3)*2048 + urz);   // gate 0 (r) or 1 (z)
  const size_t n_row  = (size_t)(4096 + urz);             // gate 2 (n), 2x dup
  bf16x8 wRZh[8], wRZl[8], wNh[8], wNl[8];
  {
    const bf16* pRZh = WhH + rz_row*2048 + koff;
    const bf16* pRZl = WhL + rz_row*2048 + koff;
    const bf16* pNh  = WhH + n_row*2048 + koff;
    const bf16* pNl  = WhL + n_row*2048 + koff;
#pragma unroll
    for (int c = 0; c < 8; c++) {
      wRZh[c] = *(const bf16x8*)(pRZh + c*32);
      wRZl[c] = *(const bf16x8*)(pRZl + c*32);
      wNh[c]  = *(const bf16x8*)(pNh  + c*32);
      wNl[c]  = *(const bf16x8*)(pNl  + c*32);
    }
#pragma unroll
    for (int c = 0; c < 8; c++) { pina(wRZh[c]); pina(wRZl[c]); pina(wNh[c]); pina(wNl[c]); }
  }

  // ---- gate-lane state (waves 0,1; lanes lm<8): unit gu, rows w*16+lk*4+k
  const bool gatelane = (w < 2) && (lm < 8);
  const int gu = u0 + lm;
  float br_ = 0.f, bz_ = 0.f, bn_ = 0.f;
  float hst[4] = {0.f, 0.f, 0.f, 0.f};
  if (gatelane) {
    br_ = bhh[gu]; bz_ = bhh[2048 + gu]; bn_ = bhh[4096 + gu];
    if (t0_abs != 0) {
#pragma unroll
      for (int k = 0; k < 4; k++)
        hst[k] = h32[(size_t)(w*16 + lk*4 + k)*2048 + gu];
    }
  }

#define GRU_MFMA(c, CUR)                                              \
  acc[0][0] = MFMA(CUR[0], wRZh[c], acc[0][0], 0,0,0);                \
  acc[0][0] = MFMA(CUR[2], wRZh[c], acc[0][0], 0,0,0);                \
  acc[0][0] = MFMA(CUR[0], wRZl[c], acc[0][0], 0,0,0);                \
  acc[0][1] = MFMA(CUR[0], wNh[c],  acc[0][1], 0,0,0);                \
  acc[0][1] = MFMA(CUR[2], wNh[c],  acc[0][1], 0,0,0);                \
  acc[0][1] = MFMA(CUR[0], wNl[c],  acc[0][1], 0,0,0);                \
  acc[1][0] = MFMA(CUR[1], wRZh[c], acc[1][0], 0,0,0);                \
  acc[1][0] = MFMA(CUR[3], wRZh[c], acc[1][0], 0,0,0);                \
  acc[1][0] = MFMA(CUR[1], wRZl[c], acc[1][0], 0,0,0);                \
  acc[1][1] = MFMA(CUR[1], wNh[c],  acc[1][1], 0,0,0);                \
  acc[1][1] = MFMA(CUR[3], wNh[c],  acc[1][1], 0,0,0);                \
  acc[1][1] = MFMA(CUR[1], wNl[c],  acc[1][1], 0,0,0);

#define KSTEP(c, CUR, NXT)                                            \
  {                                                                   \
    const bf16* q  = pa  + (c+1)*32;                                  \
    const bf16* ql = pal + (c+1)*32;                                  \
    ldg4(NXT[0], NXT[1], NXT[2], NXT[3], q, q + 32768, ql, ql + 32768); \
    asm volatile("s_waitcnt vmcnt(4)");                               \
    __builtin_amdgcn_sched_barrier(0);                                \
    GRU_MFMA(c, CUR)                                                  \
  }
#define KLAST(c, CUR)                                                 \
  {                                                                   \
    asm volatile("s_waitcnt vmcnt(0)");                               \
    __builtin_amdgcn_sched_barrier(0);                                \
    GRU_MFMA(c, CUR)                                                  \
  }

#pragma unroll 1
  for (int tt = 0; tt < 32; tt++) {
    const int t = t0_abs + tt;

    // gi prefetch (independent of h; hides under MFMA phase)
    float gv[4][3];
    if (gatelane) {
      const float* git = gi + (size_t)tt*196608;
#pragma unroll
      for (int k = 0; k < 4; k++) {
        const float* gr = git + (size_t)(w*16 + lk*4 + k)*6144 + gu;
        gv[k][0] = gr[0]; gv[k][1] = gr[2048]; gv[k][2] = gr[4096];
      }
    }

    const bf16* aH = (t == 0) ? z16 : XYEhi + (size_t)(t-1)*65536;
    const bf16* aL = (t == 0) ? z16 : XYElo + (size_t)(t-1)*65536;
    const bf16* pa  = aH + (size_t)lm*2048 + koff;
    const bf16* pal = aL + (size_t)lm*2048 + koff;

    f32x4 acc[2][2];
#pragma unroll
    for (int i = 0; i < 2; i++)
#pragma unroll
      for (int j2 = 0; j2 < 2; j2++) acc[i][j2] = (f32x4){0.f,0.f,0.f,0.f};

    bf16x8 g0[4], g1[4];
    ldg4(g0[0], g0[1], g0[2], g0[3], pa, pa + 32768, pal, pal + 32768);
    KSTEP(0, g0, g1) KSTEP(1, g1, g0) KSTEP(2, g0, g1) KSTEP(3, g1, g0)
    KSTEP(4, g0, g1) KSTEP(5, g1, g0) KSTEP(6, g0, g1) KLAST(7, g1)

    // partials -> LDS  (idx = mt*8 + frag*4 + k)
    float* mr = red + (size_t)(w*64 + l)*17;
#pragma unroll
    for (int mt = 0; mt < 2; mt++)
#pragma unroll
      for (int f = 0; f < 2; f++)
#pragma unroll
        for (int k = 0; k < 4; k++)
          mr[mt*8 + f*4 + k] = acc[mt][f][k];
    __syncthreads();

    // cross-wave reduce into plane 0 (all 512 threads, 2 (lane,idx) pairs each)
#pragma unroll
    for (int j2 = 0; j2 < 2; j2++) {
      int p = tid*2 + j2;
      int lp = p >> 4, idx = p & 15;
      float s = red[lp*17 + idx];
#pragma unroll
      for (int w2 = 1; w2 < 8; w2++) s += red[(w2*64 + lp)*17 + idx];
      red[lp*17 + idx] = s;
    }
    __syncthreads();

    // gates: wave w=mt handles rows mt*16 + lk*4 + k of its 8 units
    if (gatelane) {
#pragma unroll
      for (int k = 0; k < 4; k++) {
        float rsum = red[(lk*16 + lm)*17     + w*8 + k];
        float zsum = red[(lk*16 + lm + 8)*17 + w*8 + k];
        float nsum = red[(lk*16 + lm)*17     + w*8 + 4 + k];
        float rr = sigm(gv[k][0] + rsum + br_);
        float zz = sigm(gv[k][1] + zsum + bz_);
        float nn = tanhf(gv[k][2] + rr*(nsum + bn_));
        float hnew = (1.f - zz)*nn + zz*hst[k];
        hst[k] = hnew;
        bf16 hb = (bf16)hnew;
        int row = w*16 + lk*4 + k;
        hstgH[row][lm] = hb;
        hstgL[row][lm] = (bf16)(hnew - (float)hb);
      }
    }
    __syncthreads();   // hstg ready

    // wave 0: coherent 16B stores of this block's h_t columns (hi + lo)
    if (tid < 64) {
      int row = tid >> 1, hf = tid & 1;
      bf16x8 v = hf ? *(const bf16x8*)&hstgL[row][0] : *(const bf16x8*)&hstgH[row][0];
      bf16* dst = (hf ? XYElo : XYEhi) + (size_t)t*65536 + (size_t)row*2048 + u0;
      st_coh16(dst, v);
    }

    // grid barrier (monotone counter; all exchange stores live in wave 0,
    // so tid0's vmcnt(0) is a complete release)
    if (tt < 31) {
      if (tid == 0) {
        asm volatile("s_waitcnt vmcnt(0)");
        __hip_atomic_fetch_add(bar, 1u, __ATOMIC_RELAXED, __HIP_MEMORY_SCOPE_AGENT);
        unsigned tgt = bar_base + (unsigned)(tt + 1)*256u;
        while (__hip_atomic_load(bar, __ATOMIC_RELAXED, __HIP_MEMORY_SCOPE_AGENT) < tgt)
          __builtin_amdgcn_s_sleep(8);
      }
      __syncthreads();
    }
  }

  // drain last step's exchange stores before endpgm
  if (tid < 64) asm volatile("s_waitcnt vmcnt(0)");

  // phase handoff
  if (gatelane) {
#pragma unroll
    for (int k = 0; k < 4; k++)
      h32[(size_t)(w*16 + lk*4 + k)*2048 + gu] = hst[k];
  }
#undef GRU_MFMA
#undef KSTEP
#undef KLAST
}

// ---------------- temporal attention (reads emb hi+lo)
__global__ __launch_bounds__(256) void k_attn(
    const bf16* __restrict__ eHi, const bf16* __restrict__ eLo, // (128,32,2048)
    const float* __restrict__ A_w, const float* __restrict__ A_b,
    float* __restrict__ att_vec)    // (128,2048)
{
  __shared__ float Aw[1024];
  __shared__ float Ab[32];
  const int n = blockIdx.x, tid = threadIdx.x;
  for (int i = tid; i < 1024; i += 256) Aw[i] = A_w[i];
  if (tid < 32) Ab[tid] = A_b[tid];
  __syncthreads();
  for (int f = tid; f < 2048; f += 256) {
    float a[32];
#pragma unroll
    for (int t = 0; t < 32; t++) {
      size_t ix = (size_t)n*65536 + t*2048 + f;
      a[t] = tanhf((float)eHi[ix] + (float)eLo[ix]);
    }
    float aw[32]; float mx = -1e30f;
#pragma unroll
    for (int t2 = 0; t2 < 32; t2++) {
      float s = Ab[t2];
#pragma unroll
      for (int t = 0; t < 32; t++) s += Aw[t2*32 + t]*a[t];
      aw[t2] = s; mx = fmaxf(mx, s);
    }
    float den = 0.f, num = 0.f;
#pragma unroll
    for (int t = 0; t < 32; t++) { float e = expf(aw[t]-mx); den += e; num += e*a[t]; }
    att_vec[n*2048 + f] = tanhf(num/den);
  }
}

// ---------------- both GATv2 layers fused (fp32); block = 32-node dense subgraph
__global__ __launch_bounds__(256) void k_gat(
    const float* __restrict__ xn,
    const float* __restrict__ Wl0, const float* __restrict__ bl0,
    const float* __restrict__ Wr0, const float* __restrict__ br0,
    const float* __restrict__ at0, const float* __restrict__ bs0,
    const float* __restrict__ Wl1, const float* __restrict__ bl1,
    const float* __restrict__ Wr1, const float* __restrict__ br1,
    const float* __restrict__ at1, const float* __restrict__ bs1,
    float* __restrict__ gout)
{
  __shared__ float X[32*64];
  __shared__ float G0s[32*64];
  __shared__ float XL[32*65];
  __shared__ float XR[32*65];
  __shared__ float LG[32*32];
  __shared__ float WlT[64*64];
  __shared__ float WrT[64*64];
  __shared__ float attb[64], blb[64], brb[64], bsb[64];

  const int b = blockIdx.x, tid = threadIdx.x;
  for (int i = tid; i < 2048; i += 256) X[i] = xn[b*2048 + i];

  for (int lay = 0; lay < 2; lay++) {
    const float* Wl = lay ? Wl1 : Wl0;
    const float* Wr = lay ? Wr1 : Wr0;
    const float* bl = lay ? bl1 : bl0;
    const float* br = lay ? br1 : br0;
    const float* at = lay ? at1 : at0;
    const float* bs = lay ? bs1 : bs0;
    __syncthreads();
    for (int i = tid; i < 4096; i += 256) {
      int c = i >> 6, k = i & 63;
      WlT[k*64 + c] = Wl[i];
      WrT[k*64 + c] = Wr[i];
    }
    if (tid < 64) {
      attb[tid] = at[tid]; blb[tid] = bl[tid];
      brb[tid]  = br[tid]; bsb[tid] = bs[tid];
    }
    __syncthreads();
    const float* Xin = lay ? G0s : X;
    for (int e = tid; e < 2048; e += 256) {
      int i = e >> 6, c = e & 63;
      float sl = blb[c], sr = brb[c];
#pragma unroll 8
      for (int k = 0; k < 64; k++) {
        float xv = Xin[i*64 + k];
        sl += xv*WlT[k*64 + c];
        sr += xv*WrT[k*64 + c];
      }
      XL[i*65 + c] = sl; XR[i*65 + c] = sr;
    }
    __syncthreads();
    for (int p = tid; p < 1024; p += 256) {
      int i = p >> 5, j = p & 31;
      float s = 0.f;
#pragma unroll 8
      for (int c = 0; c < 64; c++) {
        float v = XL[i*65 + c] + XR[j*65 + c];
        v = (v > 0.f) ? v : 0.2f*v;
        s += v*attb[c];
      }
      LG[i*32 + j] = s;
    }
    __syncthreads();
    if (tid < 32) {
      int j = tid;
      float m = -1e30f;
      for (int i = 0; i < 32; i++) m = fmaxf(m, LG[i*32 + j]);
      float den = 0.f;
      for (int i = 0; i < 32; i++) den += expf(LG[i*32 + j] - m);
      float inv = 1.f/den;
      for (int i = 0; i < 32; i++) LG[i*32 + j] = expf(LG[i*32 + j] - m)*inv;
    }
    __syncthreads();
    for (int e = tid; e < 2048; e += 256) {
      int j = e >> 6, c = e & 63;
      float s = 0.f;
#pragma unroll 8
      for (int i = 0; i < 32; i++) s += LG[i*32 + j]*XL[i*65 + c];
      float val = tanhf(s + bsb[c]);
      if (lay == 0) G0s[j*64 + c] = val;
      else          gout[b*2048 + j*64 + c] = G0s[j*64 + c] + val;
    }
  }
}

// ---------------- priors[n,o,c,l] = sum_i W_caps[o,l,i]*fusion[n,c,i]
__global__ __launch_bounds__(256) void k_priors(
    const float* __restrict__ att_vec,
    const float* __restrict__ g,
    const float* __restrict__ W_caps,   // (32,64,128)
    float* __restrict__ priors)         // (128,32,32,64)
{
  __shared__ float FU[32*128];
  const int n = blockIdx.x >> 1, oh = blockIdx.x & 1, tid = threadIdx.x;
  for (int e = tid; e < 4096; e += 256) {
    int c = e >> 7, i = e & 127;
    FU[e] = (i < 64) ? att_vec[n*2048 + c*64 + i] : g[n*2048 + c*64 + (i - 64)];
  }
  __syncthreads();
  for (int oo = 0; oo < 16; oo++) {
    int o = oh*16 + oo;
    const float* W = W_caps + (size_t)o*8192;
    for (int e = tid; e < 2048; e += 256) {
      int c = e >> 6, l2 = e & 63;
      const float* Wr_ = W + l2*128;
      float s = 0.f;
#pragma unroll
      for (int i = 0; i < 128; i += 4) {
        float4 w4 = *(const float4*)(Wr_ + i);
        s += w4.x*FU[c*128 + i]     + w4.y*FU[c*128 + i + 1]
           + w4.z*FU[c*128 + i + 2] + w4.w*FU[c*128 + i + 3];
      }
      priors[(((size_t)n*32 + o)*32 + c)*64 + l2] = s;
    }
  }
}

// ---------------- dynamic routing (3 iters) + final FC
__global__ __launch_bounds__(64) void k_route(
    const float* __restrict__ priors,
    const float* __restrict__ F_w, const float* __restrict__ F_b,
    float* __restrict__ out)           // (128,32,32)
{
  __shared__ float ct[2048];
  __shared__ float fwt[2048];
  __shared__ float fbs[32];
  const int n = blockIdx.x, l = threadIdx.x;
  for (int i = l; i < 2048; i += 64) { int d2 = i >> 6, k = i & 63; fwt[k*32 + d2] = F_w[i]; }
  if (l < 32) fbs[l] = F_b[l];
  const float* PR = priors + (size_t)n*65536;

  float S[32];
#pragma unroll
  for (int o = 0; o < 32; o++) S[o] = 0.f;
  for (int c = 0; c < 32; c++) {
#pragma unroll
    for (int o = 0; o < 32; o++) S[o] += PR[(o*32 + c)*64 + l];
  }
#pragma unroll
  for (int o = 0; o < 32; o++) S[o] *= 0.03125f;

  float On[32];
  for (int rr = 0; rr < 2; rr++) {
#pragma unroll
    for (int o = 0; o < 32; o++) On[o] = 0.f;
    for (int c = 0; c < 32; c++) {
      float col[32], eo[32];
      float mx = -1e30f;
#pragma unroll
      for (int o = 0; o < 32; o++) {
        col[o] = PR[(o*32 + c)*64 + l];
        float t = col[o]*S[o];
        eo[o] = t; mx = fmaxf(mx, t);
      }
      float den = 0.f;
#pragma unroll
      for (int o = 0; o < 32; o++) { eo[o] = expf(eo[o]-mx); den += eo[o]; }
      float inv = 1.f/den;
#pragma unroll
      for (int o = 0; o < 32; o++) On[o] += eo[o]*inv*col[o];
    }
    if (rr == 0) {
#pragma unroll
      for (int o = 0; o < 32; o++) S[o] += On[o];
    }
  }
#pragma unroll
  for (int o = 0; o < 32; o++) ct[o*64 + l] = tanhf(On[o]);
  __syncthreads();
#pragma unroll
  for (int e = 0; e < 16; e++) {
    int el = l + e*64;
    int o = el >> 5, d2 = el & 31;
    float s = fbs[d2];
#pragma unroll
    for (int k = 0; k < 64; k++) s += ct[o*64 + k]*fwt[k*32 + d2];
    out[(size_t)n*1024 + el] = tanhf(s);
  }
}

// =====================================================================
extern "C" void kernel_launch(void* const* d_in, const int* in_sizes, int n_in,
                              void* d_out, int out_size, void* d_ws, size_t ws_size,
                              hipStream_t stream) {
  const float* inputs = (const float*)d_in[0];
  const float* Wih0 = (const float*)d_in[1];
  const float* Whh0 = (const float*)d_in[2];
  const float* bih0 = (const float*)d_in[3];
  const float* bhh0 = (const float*)d_in[4];
  const float* Wih1 = (const float*)d_in[5];
  const float* Whh1 = (const float*)d_in[6];
  const float* bih1 = (const float*)d_in[7];
  const float* bhh1 = (const float*)d_in[8];
  const float* A_w  = (const float*)d_in[9];
  const float* A_b  = (const float*)d_in[10];
  const float* g0_Wl = (const float*)d_in[11];
  const float* g0_bl = (const float*)d_in[12];
  const float* g0_Wr = (const float*)d_in[13];
  const float* g0_br = (const float*)d_in[14];
  const float* g0_at = (const float*)d_in[15];
  const float* g0_bs = (const float*)d_in[16];
  const float* g1_Wl = (const float*)d_in[17];
  const float* g1_bl = (const float*)d_in[18];
  const float* g1_Wr = (const float*)d_in[19];
  const float* g1_br = (const float*)d_in[20];
  const float* g1_at = (const float*)d_in[21];
  const float* g1_bs = (const float*)d_in[22];
  const float* W_caps = (const float*)d_in[23];
  const float* F_w  = (const float*)d_in[24];
  const float* F_b  = (const float*)d_in[25];
  // d_in[26] = edge_index: block-dense, not needed.

  char* ws = (char*)d_ws;
  bf16*  WihH  = (bf16*) (ws + 0);
  bf16*  WihL  = (bf16*) (ws + 25165824);
  bf16*  WhhH  = (bf16*) (ws + 50331648);
  bf16*  WhhL  = (bf16*) (ws + 75497472);
  float* gi    = (float*)(ws + 100663296);
  bf16*  XYEhi = (bf16*) (ws + 125829120);
  bf16*  XYElo = (bf16*) (ws + 142606336);
  float* h32   = (float*)(ws + 159383552);
  bf16*  z16   = (bf16*) (ws + 159645696);
  float* attv  = (float*)(ws + 159776768);
  float* g     = (float*)(ws + 160825344);
  float* priors= (float*)(ws + 0);             // overlaps Wih pair (dead at tail)
  unsigned* bar = (unsigned*)(ws + 160825344); // overlaps gbuf (dead until k_gat)

  dim3 gemm_grid(48, 8);   // N=6144/128, M=1024/128

  hipMemsetAsync(z16, 0, 131072, stream);
  hipMemsetAsync(bar, 0, 4, stream);
  k_prep<<<8192, 256, 0, stream>>>((const float4*)inputs, (bf16x4*)XYEhi, (bf16x4*)XYElo, 2097152);

  unsigned bb = 0;
  for (int layer = 0; layer < 2; layer++) {
    const float* Wih = layer ? Wih1 : Wih0;
    const float* Whh = layer ? Whh1 : Whh0;
    const float* bih = layer ? bih1 : bih0;
    const float* bhh = layer ? bhh1 : bhh0;

    k_split<<<12288, 256, 0, stream>>>((const float4*)Wih, (bf16x4*)WihH, (bf16x4*)WihL, 3145728);
    k_split<<<12288, 256, 0, stream>>>((const float4*)Whh, (bf16x4*)WhhH, (bf16x4*)WhhL, 3145728);

    for (int p = 0; p < 4; p++) {
      k_gemm3<<<gemm_grid, 256, 0, stream>>>(
          XYEhi + (size_t)p*1024*2048, XYElo + (size_t)p*1024*2048,
          WihH, WihL, bih, gi, 1024, 6144, 2048);
      k_gru_phase<<<256, 512, 0, stream>>>(WhhH, WhhL, bhh, gi, h32,
          XYEhi, XYElo, z16, p*32, bar, bb);
      bb += 31u*256u;
    }
  }

  // ---- tail (emb == XYE pair)
  k_attn<<<128, 256, 0, stream>>>(XYEhi, XYElo, A_w, A_b, attv);
  k_gat<<<128, 256, 0, stream>>>(attv,
      g0_Wl, g0_bl, g0_Wr, g0_br, g0_at, g0_bs,
      g1_Wl, g1_bl, g1_Wr, g1_br, g1_at, g1_bs, g);
  k_priors<<<256, 256, 0, stream>>>(attv, g, W_caps, priors);
  k_route<<<128, 64, 0, stream>>>(priors, F_w, F_b, (float*)d_out);
}